// Round 12
// baseline (193.117 us; speedup 1.0000x reference)
//
#include <hip/hip_runtime.h>
#include <hip/hip_bf16.h>
#include <cstdint>
#include <cstddef>

// ---------------------------------------------------------------------------
// GateLoop fused pipeline — consolidation round 2.
// prep_k: fused weight-transpose (z=0..5) + rmsnorm (z=6).
// GEMM1: 8-phase 256x256 BK=64 (round-6 verbatim).
// GEMM2: 128x128 ring-3 (round-6 verbatim).
// Scan: 3-pass, packed interleaved loads, L=32 chunks (1024 blocks, 4/CU).
// qkvg layout: cols [0,2048) k/v interleaved, [2048,4096) q/g interleaved,
// a -> fp32 apre. B=2, S=4096, D=1024 hard-coded.
// ---------------------------------------------------------------------------

typedef __bf16 bf16x8 __attribute__((ext_vector_type(8)));
typedef float f32x4 __attribute__((ext_vector_type(4)));

__device__ __forceinline__ void gload_lds16(const void* g, void* l) {
  __builtin_amdgcn_global_load_lds(
      (const __attribute__((address_space(1))) void*)g,
      (__attribute__((address_space(3))) void*)l,
      16, 0, 0);
}

__device__ __forceinline__ bf16x8 ldfrag(const unsigned short* p) {
  return *(const bf16x8*)p;
}

__device__ __forceinline__ float bfhi(unsigned int u) {
  union { unsigned int i; float f; } c; c.i = u & 0xffff0000u; return c.f;
}
__device__ __forceinline__ float bflo(unsigned int u) {
  union { unsigned int i; float f; } c; c.i = u << 16; return c.f;
}

#define MFMA16(acc_, a_, b_) \
  acc_ = __builtin_amdgcn_mfma_f32_16x16x32_bf16(a_, b_, acc_, 0, 0, 0)

// ---------------------------------------------------------------------------
// prep_k: z<6 -> weight convert+transpose with interleave row mapping
//   (k -> row 2n, v -> 2n+1, q -> 2048+2n, g -> 2048+2n+1, a -> 4096+n,
//    wo -> woT row n); z==6 -> rmsnorm for 8 rows per block.
// grid (32,32,7), block (32,8).
// ---------------------------------------------------------------------------
__global__ __launch_bounds__(256) void prep_k(
    const float* __restrict__ x, const float* __restrict__ gamma,
    const float* __restrict__ wq, const float* __restrict__ wk,
    const float* __restrict__ wv, const float* __restrict__ wa,
    const float* __restrict__ wg, const float* __restrict__ wo,
    __hip_bfloat16* __restrict__ wcatT, __hip_bfloat16* __restrict__ woT,
    __hip_bfloat16* __restrict__ xn) {
  const int tx = threadIdx.x, ty = threadIdx.y;  // (32, 8)

  if (blockIdx.z == 6) {
    // ---- rmsnorm: 8 rows per block ----
    __shared__ float wss[4];
    const int tid = ty * 32 + tx;  // 0..255
    const int row0 = (blockIdx.y * 32 + blockIdx.x) * 8;
    for (int i = 0; i < 8; ++i) {
      const int row = row0 + i;
      const float4 xv = ((const float4*)(x + (size_t)row * 1024))[tid];
      float ss = xv.x * xv.x + xv.y * xv.y + xv.z * xv.z + xv.w * xv.w;
#pragma unroll
      for (int off = 32; off >= 1; off >>= 1) ss += __shfl_xor(ss, off, 64);
      if ((tid & 63) == 0) wss[tid >> 6] = ss;
      __syncthreads();
      const float total = wss[0] + wss[1] + wss[2] + wss[3];
      const float scale = rsqrtf(total + 1e-5f) * 32.0f;  // sqrt(1024) = 32
      const float4 gv = ((const float4*)gamma)[tid];
      union { __hip_bfloat16 h[4]; ushort4 u; } ob;
      ob.h[0] = __float2bfloat16(xv.x * gv.x * scale);
      ob.h[1] = __float2bfloat16(xv.y * gv.y * scale);
      ob.h[2] = __float2bfloat16(xv.z * gv.z * scale);
      ob.h[3] = __float2bfloat16(xv.w * gv.w * scale);
      ((ushort4*)(xn + (size_t)row * 1024))[tid] = ob.u;
      __syncthreads();  // wss safe for next iteration
    }
    return;
  }

  // ---- weight transpose tile ----
  __shared__ float t[32][33];
  const float* src;
  __hip_bfloat16* dst;
  int rmul, roff;
  switch (blockIdx.z) {
    case 0: src = wq; dst = wcatT; rmul = 2; roff = 2048; break;
    case 1: src = wk; dst = wcatT; rmul = 2; roff = 0;    break;
    case 2: src = wv; dst = wcatT; rmul = 2; roff = 1;    break;
    case 3: src = wg; dst = wcatT; rmul = 2; roff = 2049; break;
    case 4: src = wa; dst = wcatT; rmul = 1; roff = 4096; break;
    default: src = wo; dst = woT;  rmul = 1; roff = 0;    break;
  }
  const int n0 = blockIdx.x * 32;
  const int k0 = blockIdx.y * 32;
#pragma unroll
  for (int i = 0; i < 32; i += 8)
    t[ty + i][tx] = src[(size_t)(k0 + ty + i) * 1024 + n0 + tx];
  __syncthreads();
#pragma unroll
  for (int i = 0; i < 32; i += 8)
    dst[(size_t)(roff + rmul * (n0 + ty + i)) * 1024 + k0 + tx] =
        __float2bfloat16(t[tx][ty + i]);
}

// ---------------------------------------------------------------------------
// gemm256p: 8-phase pipeline (round-6, unchanged).
// ---------------------------------------------------------------------------
__global__ __launch_bounds__(512, 2) void gemm256p(
    const __hip_bfloat16* __restrict__ A, const __hip_bfloat16* __restrict__ Bt,
    int M, int N, int K,
    __hip_bfloat16* __restrict__ outb, int ldb, int nbcols,
    float* __restrict__ outf, int ldf) {
  __shared__ __align__(16) unsigned short lds[65536];  // 128 KiB
  unsigned short* Asl = lds;           // [2][2][128][64] : dbuf*16384 + ht*8192
  unsigned short* Bsl = lds + 32768;

  const int tid = threadIdx.x;
  const int nwg = gridDim.x * gridDim.y;
  const int bid = blockIdx.y * gridDim.x + blockIdx.x;
  const int swz = (bid & 7) * (nwg >> 3) + (bid >> 3);
  const int brow = (swz / gridDim.x) * 256;
  const int bcol = (swz % gridDim.x) * 256;

  const unsigned short* Ag = (const unsigned short*)A + (size_t)brow * K;
  const unsigned short* Bg = (const unsigned short*)Bt + (size_t)bcol * K;

  const int sr = tid >> 3;  // 0..63
  const int sc = tid & 7;   // 16B chunk 0..7

  auto stage = [&](unsigned short* dst, const unsigned short* G, int ht, int T) {
#pragma unroll
    for (int j = 0; j < 2; ++j) {
      const int row = sr + j * 64;
      gload_lds16(G + (size_t)(ht * 128 + row) * K + T * 64 + ((sc ^ (row & 7)) << 3),
                  dst + row * 64 + sc * 8);
    }
  };

  const int lane = tid & 63;
  const int wid = tid >> 6;
  const int wr = wid >> 2;
  const int wc = wid & 3;
  const int l16 = lane & 15;
  const int k8 = lane >> 4;

  int aoff[8], boff[4];
#pragma unroll
  for (int m = 0; m < 8; ++m) {
    const int row = wr * 128 + m * 16 + l16;
    const int ht = row >> 7, hr = row & 127;
    aoff[m] = ht * 8192 + hr * 64 + ((k8 ^ (hr & 7)) << 3);
  }
#pragma unroll
  for (int n = 0; n < 4; ++n) {
    const int row = wc * 64 + n * 16 + l16;
    const int ht = row >> 7, hr = row & 127;
    boff[n] = ht * 8192 + hr * 64 + ((k8 ^ (hr & 7)) << 3);
  }

  f32x4 acc[8][4];
#pragma unroll
  for (int m = 0; m < 8; ++m)
#pragma unroll
    for (int n = 0; n < 4; ++n) acc[m][n] = (f32x4){0.f, 0.f, 0.f, 0.f};

  const int NT = K >> 6;

  stage(Asl, Ag, 0, 0);          stage(Asl + 8192, Ag, 1, 0);
  stage(Bsl, Bg, 0, 0);          stage(Bsl + 8192, Bg, 1, 0);
  stage(Bsl + 16384, Bg, 0, 1);  stage(Bsl + 16384 + 8192, Bg, 1, 1);
  asm volatile("s_waitcnt vmcnt(4)" ::: "memory");
  __builtin_amdgcn_s_barrier();

  bf16x8 aL[4][2], aH[4][2], bL[2][2], bH[2][2];

  for (int i = 0; i < NT / 2; ++i) {
    const int T1 = 2 * i + 1, T2 = 2 * i + 2, T3 = 2 * i + 3;
    const unsigned short* A0 = Asl;
    const unsigned short* B0 = Bsl;
    const unsigned short* A1 = Asl + 16384;
    const unsigned short* B1 = Bsl + 16384;

    // P1
#pragma unroll
    for (int m = 0; m < 4; ++m) {
      aL[m][0] = ldfrag(A0 + aoff[m]);
      aL[m][1] = ldfrag(A0 + (aoff[m] ^ 32));
    }
#pragma unroll
    for (int n = 0; n < 2; ++n) {
      bL[n][0] = ldfrag(B0 + boff[n]);
      bL[n][1] = ldfrag(B0 + (boff[n] ^ 32));
    }
    stage(Asl + 16384, Ag, 0, T1);
    asm volatile("s_waitcnt lgkmcnt(8)" ::: "memory");
    __builtin_amdgcn_s_barrier();
    asm volatile("s_waitcnt lgkmcnt(0)" ::: "memory");
    __builtin_amdgcn_s_setprio(1);
#pragma unroll
    for (int m = 0; m < 4; ++m)
#pragma unroll
      for (int n = 0; n < 2; ++n) {
        MFMA16(acc[m][n], aL[m][0], bL[n][0]);
        MFMA16(acc[m][n], aL[m][1], bL[n][1]);
      }
    __builtin_amdgcn_s_setprio(0);
    __builtin_amdgcn_s_barrier();

    // P2
#pragma unroll
    for (int n = 0; n < 2; ++n) {
      bH[n][0] = ldfrag(B0 + boff[2 + n]);
      bH[n][1] = ldfrag(B0 + (boff[2 + n] ^ 32));
    }
    stage(Asl + 16384 + 8192, Ag, 1, T1);
    __builtin_amdgcn_s_barrier();
    asm volatile("s_waitcnt lgkmcnt(0)" ::: "memory");
    __builtin_amdgcn_s_setprio(1);
#pragma unroll
    for (int m = 0; m < 4; ++m)
#pragma unroll
      for (int n = 0; n < 2; ++n) {
        MFMA16(acc[m][2 + n], aL[m][0], bH[n][0]);
        MFMA16(acc[m][2 + n], aL[m][1], bH[n][1]);
      }
    __builtin_amdgcn_s_setprio(0);
    __builtin_amdgcn_s_barrier();

    // P3
#pragma unroll
    for (int m = 0; m < 4; ++m) {
      aH[m][0] = ldfrag(A0 + aoff[4 + m]);
      aH[m][1] = ldfrag(A0 + (aoff[4 + m] ^ 32));
    }
    if (T2 < NT) stage(Bsl, Bg, 0, T2);
    __builtin_amdgcn_s_barrier();
    asm volatile("s_waitcnt lgkmcnt(0)" ::: "memory");
    __builtin_amdgcn_s_setprio(1);
#pragma unroll
    for (int m = 0; m < 4; ++m)
#pragma unroll
      for (int n = 0; n < 2; ++n) {
        MFMA16(acc[4 + m][2 + n], aH[m][0], bH[n][0]);
        MFMA16(acc[4 + m][2 + n], aH[m][1], bH[n][1]);
      }
    __builtin_amdgcn_s_setprio(0);
    __builtin_amdgcn_s_barrier();

    // P4
    if (T2 < NT) {
      stage(Bsl + 8192, Bg, 1, T2);
      asm volatile("s_waitcnt vmcnt(4)" ::: "memory");
    } else {
      asm volatile("s_waitcnt vmcnt(0)" ::: "memory");
    }
    __builtin_amdgcn_s_barrier();
    __builtin_amdgcn_s_setprio(1);
#pragma unroll
    for (int m = 0; m < 4; ++m)
#pragma unroll
      for (int n = 0; n < 2; ++n) {
        MFMA16(acc[4 + m][n], aH[m][0], bL[n][0]);
        MFMA16(acc[4 + m][n], aH[m][1], bL[n][1]);
      }
    __builtin_amdgcn_s_setprio(0);
    __builtin_amdgcn_s_barrier();

    // P5
#pragma unroll
    for (int m = 0; m < 4; ++m) {
      aL[m][0] = ldfrag(A1 + aoff[m]);
      aL[m][1] = ldfrag(A1 + (aoff[m] ^ 32));
    }
#pragma unroll
    for (int n = 0; n < 2; ++n) {
      bL[n][0] = ldfrag(B1 + boff[n]);
      bL[n][1] = ldfrag(B1 + (boff[n] ^ 32));
    }
    if (T2 < NT) stage(Asl, Ag, 0, T2);
    asm volatile("s_waitcnt lgkmcnt(8)" ::: "memory");
    __builtin_amdgcn_s_barrier();
    asm volatile("s_waitcnt lgkmcnt(0)" ::: "memory");
    __builtin_amdgcn_s_setprio(1);
#pragma unroll
    for (int m = 0; m < 4; ++m)
#pragma unroll
      for (int n = 0; n < 2; ++n) {
        MFMA16(acc[m][n], aL[m][0], bL[n][0]);
        MFMA16(acc[m][n], aL[m][1], bL[n][1]);
      }
    __builtin_amdgcn_s_setprio(0);
    __builtin_amdgcn_s_barrier();

    // P6
#pragma unroll
    for (int n = 0; n < 2; ++n) {
      bH[n][0] = ldfrag(B1 + boff[2 + n]);
      bH[n][1] = ldfrag(B1 + (boff[2 + n] ^ 32));
    }
    if (T2 < NT) stage(Asl + 8192, Ag, 1, T2);
    __builtin_amdgcn_s_barrier();
    asm volatile("s_waitcnt lgkmcnt(0)" ::: "memory");
    __builtin_amdgcn_s_setprio(1);
#pragma unroll
    for (int m = 0; m < 4; ++m)
#pragma unroll
      for (int n = 0; n < 2; ++n) {
        MFMA16(acc[m][2 + n], aL[m][0], bH[n][0]);
        MFMA16(acc[m][2 + n], aL[m][1], bH[n][1]);
      }
    __builtin_amdgcn_s_setprio(0);
    __builtin_amdgcn_s_barrier();

    // P7
#pragma unroll
    for (int m = 0; m < 4; ++m) {
      aH[m][0] = ldfrag(A1 + aoff[4 + m]);
      aH[m][1] = ldfrag(A1 + (aoff[4 + m] ^ 32));
    }
    if (T3 < NT) stage(Bsl + 16384, Bg, 0, T3);
    __builtin_amdgcn_s_barrier();
    asm volatile("s_waitcnt lgkmcnt(0)" ::: "memory");
    __builtin_amdgcn_s_setprio(1);
#pragma unroll
    for (int m = 0; m < 4; ++m)
#pragma unroll
      for (int n = 0; n < 2; ++n) {
        MFMA16(acc[4 + m][2 + n], aH[m][0], bH[n][0]);
        MFMA16(acc[4 + m][2 + n], aH[m][1], bH[n][1]);
      }
    __builtin_amdgcn_s_setprio(0);
    __builtin_amdgcn_s_barrier();

    // P8
    if (T3 < NT) {
      stage(Bsl + 16384 + 8192, Bg, 1, T3);
      asm volatile("s_waitcnt vmcnt(4)" ::: "memory");
    } else {
      asm volatile("s_waitcnt vmcnt(0)" ::: "memory");
    }
    __builtin_amdgcn_s_barrier();
    __builtin_amdgcn_s_setprio(1);
#pragma unroll
    for (int m = 0; m < 4; ++m)
#pragma unroll
      for (int n = 0; n < 2; ++n) {
        MFMA16(acc[4 + m][n], aH[m][0], bL[n][0]);
        MFMA16(acc[4 + m][n], aH[m][1], bL[n][1]);
      }
    __builtin_amdgcn_s_setprio(0);
    __builtin_amdgcn_s_barrier();
  }

  const int mb = brow + wr * 128 + k8 * 4;
  const int nb = bcol + wc * 64 + l16;
#pragma unroll
  for (int m = 0; m < 8; ++m) {
#pragma unroll
    for (int n = 0; n < 4; ++n) {
      const int col = nb + n * 16;
#pragma unroll
      for (int r = 0; r < 4; ++r) {
        const int row = mb + m * 16 + r;
        const float v = acc[m][n][r];
        if (col < nbcols) {
          outb[(size_t)row * ldb + col] = __float2bfloat16(v);
        } else {
          outf[(size_t)row * ldf + (col - nbcols)] = v;
        }
      }
    }
  }
}

// ---------------------------------------------------------------------------
// gemm128: 128x128 tile, ring-3, counted vmcnt (round-6, unchanged). GEMM2.
// ---------------------------------------------------------------------------
__global__ __launch_bounds__(256) void gemm128(
    const __hip_bfloat16* __restrict__ A, const __hip_bfloat16* __restrict__ Bt,
    int M, int N, int K,
    __hip_bfloat16* __restrict__ outb, int ldb, int nbcols,
    float* __restrict__ outf, int ldf) {
  __shared__ __align__(16) unsigned short As[3 * 4096];
  __shared__ __align__(16) unsigned short Bs[3 * 4096];

  const int tid = threadIdx.x;
  const int nwg = gridDim.x * gridDim.y;
  const int bid = blockIdx.y * gridDim.x + blockIdx.x;
  const int swz = (bid & 7) * (nwg >> 3) + (bid >> 3);
  const int brow = (swz / gridDim.x) * 128;
  const int bcol = (swz % gridDim.x) * 128;

  const unsigned short* Ag = (const unsigned short*)A + (size_t)brow * K;
  const unsigned short* Bg = (const unsigned short*)Bt + (size_t)bcol * K;

  const int srow = tid >> 2;
  const int gch8 = (((tid & 3) ^ ((tid >> 3) & 3)) << 3);

  auto stageAB = [&](int sl, int slot) {
    unsigned short* dA = As + slot * 4096;
    unsigned short* dB = Bs + slot * 4096;
    const int k0 = sl << 5;
    gload_lds16(Ag + (size_t)srow * K + k0 + gch8, dA + tid * 8);
    gload_lds16(Ag + (size_t)(srow + 64) * K + k0 + gch8, dA + 2048 + tid * 8);
    gload_lds16(Bg + (size_t)srow * K + k0 + gch8, dB + tid * 8);
    gload_lds16(Bg + (size_t)(srow + 64) * K + k0 + gch8, dB + 2048 + tid * 8);
  };

  const int lane = tid & 63;
  const int wid = tid >> 6;
  const int wr = wid >> 1;
  const int wc = wid & 1;
  const int l16 = lane & 15;
  const int k8 = lane >> 4;

  int aoff[4], boff[4];
#pragma unroll
  for (int m = 0; m < 4; ++m) {
    const int r = wr * 64 + m * 16 + l16;
    aoff[m] = r * 32 + ((k8 ^ ((r >> 1) & 3)) << 3);
  }
#pragma unroll
  for (int n = 0; n < 4; ++n) {
    const int r = wc * 64 + n * 16 + l16;
    boff[n] = r * 32 + ((k8 ^ ((r >> 1) & 3)) << 3);
  }

  f32x4 acc[4][4];
#pragma unroll
  for (int m = 0; m < 4; ++m)
#pragma unroll
    for (int n = 0; n < 4; ++n) acc[m][n] = (f32x4){0.f, 0.f, 0.f, 0.f};

  const int NS = K >> 5;
  stageAB(0, 0);
  stageAB(1, 1);
  asm volatile("s_waitcnt vmcnt(4)" ::: "memory");
  __builtin_amdgcn_s_barrier();

  int rs = 0, ws = 2;
  for (int s = 0; s < NS; ++s) {
    if (s + 2 < NS) stageAB(s + 2, ws);
    const unsigned short* As_s = As + rs * 4096;
    const unsigned short* Bs_s = Bs + rs * 4096;
    bf16x8 af[4], bfr[4];
#pragma unroll
    for (int m = 0; m < 4; ++m) af[m] = *(const bf16x8*)(As_s + aoff[m]);
#pragma unroll
    for (int n = 0; n < 4; ++n) bfr[n] = *(const bf16x8*)(Bs_s + boff[n]);
    __builtin_amdgcn_s_setprio(1);
#pragma unroll
    for (int m = 0; m < 4; ++m)
#pragma unroll
      for (int n = 0; n < 4; ++n)
        acc[m][n] = __builtin_amdgcn_mfma_f32_16x16x32_bf16(af[m], bfr[n], acc[m][n], 0, 0, 0);
    __builtin_amdgcn_s_setprio(0);
    if (s <= NS - 3) {
      asm volatile("s_waitcnt vmcnt(4)" ::: "memory");
      __builtin_amdgcn_s_barrier();
    } else if (s == NS - 2) {
      asm volatile("s_waitcnt vmcnt(0)" ::: "memory");
      __builtin_amdgcn_s_barrier();
    }
    rs = (rs == 2) ? 0 : rs + 1;
    ws = (ws == 2) ? 0 : ws + 1;
  }

  const int mb = brow + wr * 64 + k8 * 4;
  const int nb = bcol + wc * 64 + l16;
#pragma unroll
  for (int m = 0; m < 4; ++m) {
#pragma unroll
    for (int n = 0; n < 4; ++n) {
      const int col = nb + n * 16;
#pragma unroll
      for (int r = 0; r < 4; ++r) {
        const int row = mb + m * 16 + r;
        const float v = acc[m][n][r];
        if (col < nbcols) {
          outb[(size_t)row * ldb + col] = __float2bfloat16(v);
        } else {
          outf[(size_t)row * ldf + (col - nbcols)] = v;
        }
      }
    }
  }
}

// ---------------------------------------------------------------------------
// Scan pass 1: per-chunk local scan, L=32. grid (256,4) x 256 thr (4 blk/CU).
// blockIdx.x = b*128 + chunk. kv packed 4B (low=k, high=v).
// ---------------------------------------------------------------------------
__global__ __launch_bounds__(256) void scan_pass1(
    const __hip_bfloat16* __restrict__ qkvg, const float* __restrict__ apre,
    float* __restrict__ Asum, float* __restrict__ Ysum) {
  const int bc = blockIdx.x;           // b*128 + chunk
  const int d = blockIdx.y * 256 + threadIdx.x;
  const size_t rowbase = (size_t)(bc >> 7) * 4096 + (size_t)(bc & 127) * 32;
  const unsigned int* kvp = (const unsigned int*)qkvg;  // row = 2048 uints
  float y = 0.f, Ap = 1.f;
  for (int s = 0; s < 32; ++s) {
    const size_t r = rowbase + s;
    const unsigned int kv = kvp[r * 2048 + d];
    const float ap = apre[r * 1024 + d];
    const float a = 1.f / (1.f + __expf(-ap));
    y = fmaf(a, y, bflo(kv) * bfhi(kv));
    Ap *= a;
  }
  Asum[(size_t)bc * 1024 + d] = Ap;
  Ysum[(size_t)bc * 1024 + d] = y;
}

// ---------------------------------------------------------------------------
// Scan pass 2: carry recurrence across 128 chunks per sequence.
// ---------------------------------------------------------------------------
__global__ __launch_bounds__(256) void scan_pass2(
    const float* __restrict__ Asum, const float* __restrict__ Ysum,
    float* __restrict__ carry) {
  const int idx = blockIdx.x * 256 + threadIdx.x;  // 0..2047
  const int b = idx >> 10, d = idx & 1023;
  float y = 0.f;
  for (int c = 0; c < 128; ++c) {
    const size_t o = (size_t)(b * 128 + c) * 1024 + d;
    carry[o] = y;
    y = fmaf(Asum[o], y, Ysum[o]);
  }
}

// ---------------------------------------------------------------------------
// Scan pass 3: rescan with carry-in, write yact. grid (256,4) x 256 thr.
// qg packed 4B (low=q, high=g).
// ---------------------------------------------------------------------------
__global__ __launch_bounds__(256) void scan_pass3(
    const __hip_bfloat16* __restrict__ qkvg, const float* __restrict__ apre,
    const float* __restrict__ carry, __hip_bfloat16* __restrict__ yact) {
  const int bc = blockIdx.x;
  const int d = blockIdx.y * 256 + threadIdx.x;
  const size_t rowbase = (size_t)(bc >> 7) * 4096 + (size_t)(bc & 127) * 32;
  float y = carry[(size_t)bc * 1024 + d];
  const unsigned int* kvp = (const unsigned int*)qkvg;
  for (int s = 0; s < 32; ++s) {
    const size_t r = rowbase + s;
    const unsigned int kv = kvp[r * 2048 + d];
    const unsigned int qg = kvp[r * 2048 + 1024 + d];
    const float ap = apre[r * 1024 + d];
    const float a = 1.f / (1.f + __expf(-ap));
    y = fmaf(a, y, bflo(kv) * bfhi(kv));
    const float gg = bfhi(qg);
    const float sg = 1.f / (1.f + __expf(-gg));
    yact[r * 1024 + d] = __float2bfloat16(bflo(qg) * y * gg * sg);
  }
}

// ---------------------------------------------------------------------------
// launch
// ---------------------------------------------------------------------------
extern "C" void kernel_launch(void* const* d_in, const int* in_sizes, int n_in,
                              void* d_out, int out_size, void* d_ws, size_t ws_size,
                              hipStream_t stream) {
  const float* x     = (const float*)d_in[0];
  const float* gamma = (const float*)d_in[1];
  const float* wq    = (const float*)d_in[2];
  const float* wk    = (const float*)d_in[3];
  const float* wv    = (const float*)d_in[4];
  const float* wa    = (const float*)d_in[5];
  const float* wg    = (const float*)d_in[6];
  const float* wo    = (const float*)d_in[7];
  float* out = (float*)d_out;

  char* ws = (char*)d_ws;
  __hip_bfloat16* wcatT = (__hip_bfloat16*)(ws);              // 5120x1024 bf16
  __hip_bfloat16* woT   = (__hip_bfloat16*)(ws + 10485760);   // 1024x1024 bf16
  __hip_bfloat16* xn    = (__hip_bfloat16*)(ws + 12582912);   // 8192x1024 bf16
  __hip_bfloat16* qkvg  = (__hip_bfloat16*)(ws + 29360128);   // 8192x4096 bf16
  float*          apre  = (float*)(ws + 96468992);            // 8192x1024 f32
  __hip_bfloat16* yact  = (__hip_bfloat16*)(ws + 130023424);  // 8192x1024 bf16
  // Asum/Ysum/carry (256x1024 f32 = 1 MB each) reuse xn's region — xn is
  // dead after gemm256p completes (stream-ordered before scan_pass1).
  float*          Asum  = (float*)(ws + 12582912);
  float*          Ysum  = (float*)(ws + 12582912 + 1048576);
  float*          carry = (float*)(ws + 12582912 + 2097152);

  prep_k<<<dim3(32, 32, 7), dim3(32, 8, 1), 0, stream>>>(
      x, gamma, wq, wk, wv, wa, wg, wo, wcatT, woT, xn);
  gemm256p<<<dim3(20, 32), dim3(512), 0, stream>>>(
      xn, wcatT, 8192, 5120, 1024, qkvg, 4096, 4096, apre, 1024);
  scan_pass1<<<dim3(256, 4), dim3(256), 0, stream>>>(qkvg, apre, Asum, Ysum);
  scan_pass2<<<dim3(8), dim3(256), 0, stream>>>(Asum, Ysum, carry);
  scan_pass3<<<dim3(256, 4), dim3(256), 0, stream>>>(qkvg, apre, carry, yact);
  gemm128<<<dim3(8, 64), dim3(256), 0, stream>>>(
      yact, woT, 8192, 1024, 1024, (__hip_bfloat16*)nullptr, 0, 0, out, 1024);
}

// Round 13
// 188.207 us; speedup vs baseline: 1.0261x; 1.0261x over previous
//
#include <hip/hip_runtime.h>
#include <hip/hip_bf16.h>
#include <cstdint>
#include <cstddef>

// ---------------------------------------------------------------------------
// GateLoop fused pipeline — round-11 optimum (session best: 188.2 us).
// GEMM1: 8-phase 256x256 BK=64 (round-6 verbatim, best of 7 variants).
// GEMM2: 128x128 ring-3 (round-6 verbatim).
// Scan: 3-pass, packed interleaved loads, L=64 chunks (512 blocks, 2/CU).
// qkvg layout: cols [0,2048) k/v interleaved, [2048,4096) q/g interleaved,
// a -> fp32 apre. B=2, S=4096, D=1024 hard-coded.
// ---------------------------------------------------------------------------

typedef __bf16 bf16x8 __attribute__((ext_vector_type(8)));
typedef float f32x4 __attribute__((ext_vector_type(4)));

__device__ __forceinline__ void gload_lds16(const void* g, void* l) {
  __builtin_amdgcn_global_load_lds(
      (const __attribute__((address_space(1))) void*)g,
      (__attribute__((address_space(3))) void*)l,
      16, 0, 0);
}

__device__ __forceinline__ bf16x8 ldfrag(const unsigned short* p) {
  return *(const bf16x8*)p;
}

__device__ __forceinline__ float bfhi(unsigned int u) {
  union { unsigned int i; float f; } c; c.i = u & 0xffff0000u; return c.f;
}
__device__ __forceinline__ float bflo(unsigned int u) {
  union { unsigned int i; float f; } c; c.i = u << 16; return c.f;
}

#define MFMA16(acc_, a_, b_) \
  acc_ = __builtin_amdgcn_mfma_f32_16x16x32_bf16(a_, b_, acc_, 0, 0, 0)

// ---------------------------------------------------------------------------
// Weight convert + transpose with interleave row mapping:
//   k -> row 2n, v -> row 2n+1, q -> row 2048+2n, g -> row 2048+2n+1,
//   a -> row 4096+n, wo -> woT row n.
// ---------------------------------------------------------------------------
__global__ __launch_bounds__(256) void wconv_k(
    const float* __restrict__ wq, const float* __restrict__ wk,
    const float* __restrict__ wv, const float* __restrict__ wa,
    const float* __restrict__ wg, const float* __restrict__ wo,
    __hip_bfloat16* __restrict__ wcatT, __hip_bfloat16* __restrict__ woT) {
  __shared__ float t[32][33];
  const float* src;
  __hip_bfloat16* dst;
  int rmul, roff;
  switch (blockIdx.z) {
    case 0: src = wq; dst = wcatT; rmul = 2; roff = 2048; break;
    case 1: src = wk; dst = wcatT; rmul = 2; roff = 0;    break;
    case 2: src = wv; dst = wcatT; rmul = 2; roff = 1;    break;
    case 3: src = wg; dst = wcatT; rmul = 2; roff = 2049; break;
    case 4: src = wa; dst = wcatT; rmul = 1; roff = 4096; break;
    default: src = wo; dst = woT;  rmul = 1; roff = 0;    break;
  }
  const int n0 = blockIdx.x * 32;
  const int k0 = blockIdx.y * 32;
  const int tx = threadIdx.x, ty = threadIdx.y;  // (32, 8)
#pragma unroll
  for (int i = 0; i < 32; i += 8)
    t[ty + i][tx] = src[(size_t)(k0 + ty + i) * 1024 + n0 + tx];
  __syncthreads();
#pragma unroll
  for (int i = 0; i < 32; i += 8)
    dst[(size_t)(roff + rmul * (n0 + ty + i)) * 1024 + k0 + tx] =
        __float2bfloat16(t[tx][ty + i]);
}

// ---------------------------------------------------------------------------
// RMSNorm (sum-of-squares variant): xn = x * gamma * sqrt(D) * rsqrt(ss+eps)
// ---------------------------------------------------------------------------
__global__ __launch_bounds__(256) void rmsnorm_k(
    const float* __restrict__ x, const float* __restrict__ gamma,
    __hip_bfloat16* __restrict__ xn) {
  const int row = blockIdx.x;
  const int tid = threadIdx.x;
  const float4 xv = ((const float4*)(x + (size_t)row * 1024))[tid];
  float ss = xv.x * xv.x + xv.y * xv.y + xv.z * xv.z + xv.w * xv.w;
#pragma unroll
  for (int off = 32; off >= 1; off >>= 1) ss += __shfl_xor(ss, off, 64);
  __shared__ float wss[4];
  if ((tid & 63) == 0) wss[tid >> 6] = ss;
  __syncthreads();
  const float total = wss[0] + wss[1] + wss[2] + wss[3];
  const float scale = rsqrtf(total + 1e-5f) * 32.0f;  // sqrt(1024) = 32
  const float4 gv = ((const float4*)gamma)[tid];
  union { __hip_bfloat16 h[4]; ushort4 u; } ob;
  ob.h[0] = __float2bfloat16(xv.x * gv.x * scale);
  ob.h[1] = __float2bfloat16(xv.y * gv.y * scale);
  ob.h[2] = __float2bfloat16(xv.z * gv.z * scale);
  ob.h[3] = __float2bfloat16(xv.w * gv.w * scale);
  ((ushort4*)(xn + (size_t)row * 1024))[tid] = ob.u;
}

// ---------------------------------------------------------------------------
// gemm256p: 8-phase pipeline (round-6, unchanged).
// ---------------------------------------------------------------------------
__global__ __launch_bounds__(512, 2) void gemm256p(
    const __hip_bfloat16* __restrict__ A, const __hip_bfloat16* __restrict__ Bt,
    int M, int N, int K,
    __hip_bfloat16* __restrict__ outb, int ldb, int nbcols,
    float* __restrict__ outf, int ldf) {
  __shared__ __align__(16) unsigned short lds[65536];  // 128 KiB
  unsigned short* Asl = lds;           // [2][2][128][64] : dbuf*16384 + ht*8192
  unsigned short* Bsl = lds + 32768;

  const int tid = threadIdx.x;
  const int nwg = gridDim.x * gridDim.y;
  const int bid = blockIdx.y * gridDim.x + blockIdx.x;
  const int swz = (bid & 7) * (nwg >> 3) + (bid >> 3);
  const int brow = (swz / gridDim.x) * 256;
  const int bcol = (swz % gridDim.x) * 256;

  const unsigned short* Ag = (const unsigned short*)A + (size_t)brow * K;
  const unsigned short* Bg = (const unsigned short*)Bt + (size_t)bcol * K;

  const int sr = tid >> 3;  // 0..63
  const int sc = tid & 7;   // 16B chunk 0..7

  auto stage = [&](unsigned short* dst, const unsigned short* G, int ht, int T) {
#pragma unroll
    for (int j = 0; j < 2; ++j) {
      const int row = sr + j * 64;
      gload_lds16(G + (size_t)(ht * 128 + row) * K + T * 64 + ((sc ^ (row & 7)) << 3),
                  dst + row * 64 + sc * 8);
    }
  };

  const int lane = tid & 63;
  const int wid = tid >> 6;
  const int wr = wid >> 2;
  const int wc = wid & 3;
  const int l16 = lane & 15;
  const int k8 = lane >> 4;

  int aoff[8], boff[4];
#pragma unroll
  for (int m = 0; m < 8; ++m) {
    const int row = wr * 128 + m * 16 + l16;
    const int ht = row >> 7, hr = row & 127;
    aoff[m] = ht * 8192 + hr * 64 + ((k8 ^ (hr & 7)) << 3);
  }
#pragma unroll
  for (int n = 0; n < 4; ++n) {
    const int row = wc * 64 + n * 16 + l16;
    const int ht = row >> 7, hr = row & 127;
    boff[n] = ht * 8192 + hr * 64 + ((k8 ^ (hr & 7)) << 3);
  }

  f32x4 acc[8][4];
#pragma unroll
  for (int m = 0; m < 8; ++m)
#pragma unroll
    for (int n = 0; n < 4; ++n) acc[m][n] = (f32x4){0.f, 0.f, 0.f, 0.f};

  const int NT = K >> 6;

  stage(Asl, Ag, 0, 0);          stage(Asl + 8192, Ag, 1, 0);
  stage(Bsl, Bg, 0, 0);          stage(Bsl + 8192, Bg, 1, 0);
  stage(Bsl + 16384, Bg, 0, 1);  stage(Bsl + 16384 + 8192, Bg, 1, 1);
  asm volatile("s_waitcnt vmcnt(4)" ::: "memory");
  __builtin_amdgcn_s_barrier();

  bf16x8 aL[4][2], aH[4][2], bL[2][2], bH[2][2];

  for (int i = 0; i < NT / 2; ++i) {
    const int T1 = 2 * i + 1, T2 = 2 * i + 2, T3 = 2 * i + 3;
    const unsigned short* A0 = Asl;
    const unsigned short* B0 = Bsl;
    const unsigned short* A1 = Asl + 16384;
    const unsigned short* B1 = Bsl + 16384;

    // P1
#pragma unroll
    for (int m = 0; m < 4; ++m) {
      aL[m][0] = ldfrag(A0 + aoff[m]);
      aL[m][1] = ldfrag(A0 + (aoff[m] ^ 32));
    }
#pragma unroll
    for (int n = 0; n < 2; ++n) {
      bL[n][0] = ldfrag(B0 + boff[n]);
      bL[n][1] = ldfrag(B0 + (boff[n] ^ 32));
    }
    stage(Asl + 16384, Ag, 0, T1);
    asm volatile("s_waitcnt lgkmcnt(8)" ::: "memory");
    __builtin_amdgcn_s_barrier();
    asm volatile("s_waitcnt lgkmcnt(0)" ::: "memory");
    __builtin_amdgcn_s_setprio(1);
#pragma unroll
    for (int m = 0; m < 4; ++m)
#pragma unroll
      for (int n = 0; n < 2; ++n) {
        MFMA16(acc[m][n], aL[m][0], bL[n][0]);
        MFMA16(acc[m][n], aL[m][1], bL[n][1]);
      }
    __builtin_amdgcn_s_setprio(0);
    __builtin_amdgcn_s_barrier();

    // P2
#pragma unroll
    for (int n = 0; n < 2; ++n) {
      bH[n][0] = ldfrag(B0 + boff[2 + n]);
      bH[n][1] = ldfrag(B0 + (boff[2 + n] ^ 32));
    }
    stage(Asl + 16384 + 8192, Ag, 1, T1);
    __builtin_amdgcn_s_barrier();
    asm volatile("s_waitcnt lgkmcnt(0)" ::: "memory");
    __builtin_amdgcn_s_setprio(1);
#pragma unroll
    for (int m = 0; m < 4; ++m)
#pragma unroll
      for (int n = 0; n < 2; ++n) {
        MFMA16(acc[m][2 + n], aL[m][0], bH[n][0]);
        MFMA16(acc[m][2 + n], aL[m][1], bH[n][1]);
      }
    __builtin_amdgcn_s_setprio(0);
    __builtin_amdgcn_s_barrier();

    // P3
#pragma unroll
    for (int m = 0; m < 4; ++m) {
      aH[m][0] = ldfrag(A0 + aoff[4 + m]);
      aH[m][1] = ldfrag(A0 + (aoff[4 + m] ^ 32));
    }
    if (T2 < NT) stage(Bsl, Bg, 0, T2);
    __builtin_amdgcn_s_barrier();
    asm volatile("s_waitcnt lgkmcnt(0)" ::: "memory");
    __builtin_amdgcn_s_setprio(1);
#pragma unroll
    for (int m = 0; m < 4; ++m)
#pragma unroll
      for (int n = 0; n < 2; ++n) {
        MFMA16(acc[4 + m][2 + n], aH[m][0], bH[n][0]);
        MFMA16(acc[4 + m][2 + n], aH[m][1], bH[n][1]);
      }
    __builtin_amdgcn_s_setprio(0);
    __builtin_amdgcn_s_barrier();

    // P4
    if (T2 < NT) {
      stage(Bsl + 8192, Bg, 1, T2);
      asm volatile("s_waitcnt vmcnt(4)" ::: "memory");
    } else {
      asm volatile("s_waitcnt vmcnt(0)" ::: "memory");
    }
    __builtin_amdgcn_s_barrier();
    __builtin_amdgcn_s_setprio(1);
#pragma unroll
    for (int m = 0; m < 4; ++m)
#pragma unroll
      for (int n = 0; n < 2; ++n) {
        MFMA16(acc[4 + m][n], aH[m][0], bL[n][0]);
        MFMA16(acc[4 + m][n], aH[m][1], bL[n][1]);
      }
    __builtin_amdgcn_s_setprio(0);
    __builtin_amdgcn_s_barrier();

    // P5
#pragma unroll
    for (int m = 0; m < 4; ++m) {
      aL[m][0] = ldfrag(A1 + aoff[m]);
      aL[m][1] = ldfrag(A1 + (aoff[m] ^ 32));
    }
#pragma unroll
    for (int n = 0; n < 2; ++n) {
      bL[n][0] = ldfrag(B1 + boff[n]);
      bL[n][1] = ldfrag(B1 + (boff[n] ^ 32));
    }
    if (T2 < NT) stage(Asl, Ag, 0, T2);
    asm volatile("s_waitcnt lgkmcnt(8)" ::: "memory");
    __builtin_amdgcn_s_barrier();
    asm volatile("s_waitcnt lgkmcnt(0)" ::: "memory");
    __builtin_amdgcn_s_setprio(1);
#pragma unroll
    for (int m = 0; m < 4; ++m)
#pragma unroll
      for (int n = 0; n < 2; ++n) {
        MFMA16(acc[m][n], aL[m][0], bL[n][0]);
        MFMA16(acc[m][n], aL[m][1], bL[n][1]);
      }
    __builtin_amdgcn_s_setprio(0);
    __builtin_amdgcn_s_barrier();

    // P6
#pragma unroll
    for (int n = 0; n < 2; ++n) {
      bH[n][0] = ldfrag(B1 + boff[2 + n]);
      bH[n][1] = ldfrag(B1 + (boff[2 + n] ^ 32));
    }
    if (T2 < NT) stage(Asl + 8192, Ag, 1, T2);
    __builtin_amdgcn_s_barrier();
    asm volatile("s_waitcnt lgkmcnt(0)" ::: "memory");
    __builtin_amdgcn_s_setprio(1);
#pragma unroll
    for (int m = 0; m < 4; ++m)
#pragma unroll
      for (int n = 0; n < 2; ++n) {
        MFMA16(acc[m][2 + n], aL[m][0], bH[n][0]);
        MFMA16(acc[m][2 + n], aL[m][1], bH[n][1]);
      }
    __builtin_amdgcn_s_setprio(0);
    __builtin_amdgcn_s_barrier();

    // P7
#pragma unroll
    for (int m = 0; m < 4; ++m) {
      aH[m][0] = ldfrag(A1 + aoff[4 + m]);
      aH[m][1] = ldfrag(A1 + (aoff[4 + m] ^ 32));
    }
    if (T3 < NT) stage(Bsl + 16384, Bg, 0, T3);
    __builtin_amdgcn_s_barrier();
    asm volatile("s_waitcnt lgkmcnt(0)" ::: "memory");
    __builtin_amdgcn_s_setprio(1);
#pragma unroll
    for (int m = 0; m < 4; ++m)
#pragma unroll
      for (int n = 0; n < 2; ++n) {
        MFMA16(acc[4 + m][2 + n], aH[m][0], bH[n][0]);
        MFMA16(acc[4 + m][2 + n], aH[m][1], bH[n][1]);
      }
    __builtin_amdgcn_s_setprio(0);
    __builtin_amdgcn_s_barrier();

    // P8
    if (T3 < NT) {
      stage(Bsl + 16384 + 8192, Bg, 1, T3);
      asm volatile("s_waitcnt vmcnt(4)" ::: "memory");
    } else {
      asm volatile("s_waitcnt vmcnt(0)" ::: "memory");
    }
    __builtin_amdgcn_s_barrier();
    __builtin_amdgcn_s_setprio(1);
#pragma unroll
    for (int m = 0; m < 4; ++m)
#pragma unroll
      for (int n = 0; n < 2; ++n) {
        MFMA16(acc[4 + m][n], aH[m][0], bL[n][0]);
        MFMA16(acc[4 + m][n], aH[m][1], bL[n][1]);
      }
    __builtin_amdgcn_s_setprio(0);
    __builtin_amdgcn_s_barrier();
  }

  const int mb = brow + wr * 128 + k8 * 4;
  const int nb = bcol + wc * 64 + l16;
#pragma unroll
  for (int m = 0; m < 8; ++m) {
#pragma unroll
    for (int n = 0; n < 4; ++n) {
      const int col = nb + n * 16;
#pragma unroll
      for (int r = 0; r < 4; ++r) {
        const int row = mb + m * 16 + r;
        const float v = acc[m][n][r];
        if (col < nbcols) {
          outb[(size_t)row * ldb + col] = __float2bfloat16(v);
        } else {
          outf[(size_t)row * ldf + (col - nbcols)] = v;
        }
      }
    }
  }
}

// ---------------------------------------------------------------------------
// gemm128: 128x128 tile, ring-3, counted vmcnt (round-6, unchanged). GEMM2.
// ---------------------------------------------------------------------------
__global__ __launch_bounds__(256) void gemm128(
    const __hip_bfloat16* __restrict__ A, const __hip_bfloat16* __restrict__ Bt,
    int M, int N, int K,
    __hip_bfloat16* __restrict__ outb, int ldb, int nbcols,
    float* __restrict__ outf, int ldf) {
  __shared__ __align__(16) unsigned short As[3 * 4096];
  __shared__ __align__(16) unsigned short Bs[3 * 4096];

  const int tid = threadIdx.x;
  const int nwg = gridDim.x * gridDim.y;
  const int bid = blockIdx.y * gridDim.x + blockIdx.x;
  const int swz = (bid & 7) * (nwg >> 3) + (bid >> 3);
  const int brow = (swz / gridDim.x) * 128;
  const int bcol = (swz % gridDim.x) * 128;

  const unsigned short* Ag = (const unsigned short*)A + (size_t)brow * K;
  const unsigned short* Bg = (const unsigned short*)Bt + (size_t)bcol * K;

  const int srow = tid >> 2;
  const int gch8 = (((tid & 3) ^ ((tid >> 3) & 3)) << 3);

  auto stageAB = [&](int sl, int slot) {
    unsigned short* dA = As + slot * 4096;
    unsigned short* dB = Bs + slot * 4096;
    const int k0 = sl << 5;
    gload_lds16(Ag + (size_t)srow * K + k0 + gch8, dA + tid * 8);
    gload_lds16(Ag + (size_t)(srow + 64) * K + k0 + gch8, dA + 2048 + tid * 8);
    gload_lds16(Bg + (size_t)srow * K + k0 + gch8, dB + tid * 8);
    gload_lds16(Bg + (size_t)(srow + 64) * K + k0 + gch8, dB + 2048 + tid * 8);
  };

  const int lane = tid & 63;
  const int wid = tid >> 6;
  const int wr = wid >> 1;
  const int wc = wid & 1;
  const int l16 = lane & 15;
  const int k8 = lane >> 4;

  int aoff[4], boff[4];
#pragma unroll
  for (int m = 0; m < 4; ++m) {
    const int r = wr * 64 + m * 16 + l16;
    aoff[m] = r * 32 + ((k8 ^ ((r >> 1) & 3)) << 3);
  }
#pragma unroll
  for (int n = 0; n < 4; ++n) {
    const int r = wc * 64 + n * 16 + l16;
    boff[n] = r * 32 + ((k8 ^ ((r >> 1) & 3)) << 3);
  }

  f32x4 acc[4][4];
#pragma unroll
  for (int m = 0; m < 4; ++m)
#pragma unroll
    for (int n = 0; n < 4; ++n) acc[m][n] = (f32x4){0.f, 0.f, 0.f, 0.f};

  const int NS = K >> 5;
  stageAB(0, 0);
  stageAB(1, 1);
  asm volatile("s_waitcnt vmcnt(4)" ::: "memory");
  __builtin_amdgcn_s_barrier();

  int rs = 0, ws = 2;
  for (int s = 0; s < NS; ++s) {
    if (s + 2 < NS) stageAB(s + 2, ws);
    const unsigned short* As_s = As + rs * 4096;
    const unsigned short* Bs_s = Bs + rs * 4096;
    bf16x8 af[4], bfr[4];
#pragma unroll
    for (int m = 0; m < 4; ++m) af[m] = *(const bf16x8*)(As_s + aoff[m]);
#pragma unroll
    for (int n = 0; n < 4; ++n) bfr[n] = *(const bf16x8*)(Bs_s + boff[n]);
    __builtin_amdgcn_s_setprio(1);
#pragma unroll
    for (int m = 0; m < 4; ++m)
#pragma unroll
      for (int n = 0; n < 4; ++n)
        acc[m][n] = __builtin_amdgcn_mfma_f32_16x16x32_bf16(af[m], bfr[n], acc[m][n], 0, 0, 0);
    __builtin_amdgcn_s_setprio(0);
    if (s <= NS - 3) {
      asm volatile("s_waitcnt vmcnt(4)" ::: "memory");
      __builtin_amdgcn_s_barrier();
    } else if (s == NS - 2) {
      asm volatile("s_waitcnt vmcnt(0)" ::: "memory");
      __builtin_amdgcn_s_barrier();
    }
    rs = (rs == 2) ? 0 : rs + 1;
    ws = (ws == 2) ? 0 : ws + 1;
  }

  const int mb = brow + wr * 64 + k8 * 4;
  const int nb = bcol + wc * 64 + l16;
#pragma unroll
  for (int m = 0; m < 4; ++m) {
#pragma unroll
    for (int n = 0; n < 4; ++n) {
      const int col = nb + n * 16;
#pragma unroll
      for (int r = 0; r < 4; ++r) {
        const int row = mb + m * 16 + r;
        const float v = acc[m][n][r];
        if (col < nbcols) {
          outb[(size_t)row * ldb + col] = __float2bfloat16(v);
        } else {
          outf[(size_t)row * ldf + (col - nbcols)] = v;
        }
      }
    }
  }
}

// ---------------------------------------------------------------------------
// Scan pass 1: per-chunk local scan, L=64. grid (128,4) x 256 thr (2 blk/CU).
// blockIdx.x = b*64 + chunk. kv packed 4B (low=k, high=v).
// ---------------------------------------------------------------------------
__global__ __launch_bounds__(256) void scan_pass1(
    const __hip_bfloat16* __restrict__ qkvg, const float* __restrict__ apre,
    float* __restrict__ Asum, float* __restrict__ Ysum) {
  const int bc = blockIdx.x;           // b*64 + chunk
  const int d = blockIdx.y * 256 + threadIdx.x;
  const size_t rowbase = (size_t)(bc >> 6) * 4096 + (size_t)(bc & 63) * 64;
  const unsigned int* kvp = (const unsigned int*)qkvg;  // row = 2048 uints
  float y = 0.f, Ap = 1.f;
  for (int s = 0; s < 64; ++s) {
    const size_t r = rowbase + s;
    const unsigned int kv = kvp[r * 2048 + d];
    const float ap = apre[r * 1024 + d];
    const float a = 1.f / (1.f + __expf(-ap));
    y = fmaf(a, y, bflo(kv) * bfhi(kv));
    Ap *= a;
  }
  Asum[(size_t)bc * 1024 + d] = Ap;
  Ysum[(size_t)bc * 1024 + d] = y;
}

// ---------------------------------------------------------------------------
// Scan pass 2: carry recurrence across 64 chunks per sequence.
// ---------------------------------------------------------------------------
__global__ __launch_bounds__(256) void scan_pass2(
    const float* __restrict__ Asum, const float* __restrict__ Ysum,
    float* __restrict__ carry) {
  const int idx = blockIdx.x * 256 + threadIdx.x;  // 0..2047
  const int b = idx >> 10, d = idx & 1023;
  float y = 0.f;
  for (int c = 0; c < 64; ++c) {
    const size_t o = (size_t)(b * 64 + c) * 1024 + d;
    carry[o] = y;
    y = fmaf(Asum[o], y, Ysum[o]);
  }
}

// ---------------------------------------------------------------------------
// Scan pass 3: rescan with carry-in, write yact. grid (128,4) x 256 thr.
// qg packed 4B (low=q, high=g).
// ---------------------------------------------------------------------------
__global__ __launch_bounds__(256) void scan_pass3(
    const __hip_bfloat16* __restrict__ qkvg, const float* __restrict__ apre,
    const float* __restrict__ carry, __hip_bfloat16* __restrict__ yact) {
  const int bc = blockIdx.x;
  const int d = blockIdx.y * 256 + threadIdx.x;
  const size_t rowbase = (size_t)(bc >> 6) * 4096 + (size_t)(bc & 63) * 64;
  float y = carry[(size_t)bc * 1024 + d];
  const unsigned int* kvp = (const unsigned int*)qkvg;
  for (int s = 0; s < 64; ++s) {
    const size_t r = rowbase + s;
    const unsigned int kv = kvp[r * 2048 + d];
    const unsigned int qg = kvp[r * 2048 + 1024 + d];
    const float ap = apre[r * 1024 + d];
    const float a = 1.f / (1.f + __expf(-ap));
    y = fmaf(a, y, bflo(kv) * bfhi(kv));
    const float gg = bfhi(qg);
    const float sg = 1.f / (1.f + __expf(-gg));
    yact[r * 1024 + d] = __float2bfloat16(bflo(qg) * y * gg * sg);
  }
}

// ---------------------------------------------------------------------------
// launch
// ---------------------------------------------------------------------------
extern "C" void kernel_launch(void* const* d_in, const int* in_sizes, int n_in,
                              void* d_out, int out_size, void* d_ws, size_t ws_size,
                              hipStream_t stream) {
  const float* x     = (const float*)d_in[0];
  const float* gamma = (const float*)d_in[1];
  const float* wq    = (const float*)d_in[2];
  const float* wk    = (const float*)d_in[3];
  const float* wv    = (const float*)d_in[4];
  const float* wa    = (const float*)d_in[5];
  const float* wg    = (const float*)d_in[6];
  const float* wo    = (const float*)d_in[7];
  float* out = (float*)d_out;

  char* ws = (char*)d_ws;
  __hip_bfloat16* wcatT = (__hip_bfloat16*)(ws);              // 5120x1024 bf16
  __hip_bfloat16* woT   = (__hip_bfloat16*)(ws + 10485760);   // 1024x1024 bf16
  __hip_bfloat16* xn    = (__hip_bfloat16*)(ws + 12582912);   // 8192x1024 bf16
  __hip_bfloat16* qkvg  = (__hip_bfloat16*)(ws + 29360128);   // 8192x4096 bf16
  float*          apre  = (float*)(ws + 96468992);            // 8192x1024 f32
  __hip_bfloat16* yact  = (__hip_bfloat16*)(ws + 130023424);  // 8192x1024 bf16
  // Asum/Ysum/carry (128x1024 f32 = 512 KB each) reuse xn's region — xn is
  // dead after gemm256p completes (stream-ordered before scan_pass1).
  float*          Asum  = (float*)(ws + 12582912);
  float*          Ysum  = (float*)(ws + 12582912 + 524288);
  float*          carry = (float*)(ws + 12582912 + 1048576);

  wconv_k<<<dim3(32, 32, 6), dim3(32, 8, 1), 0, stream>>>(wq, wk, wv, wa, wg, wo, wcatT, woT);
  rmsnorm_k<<<dim3(8192), dim3(256), 0, stream>>>(x, gamma, xn);
  gemm256p<<<dim3(20, 32), dim3(512), 0, stream>>>(
      xn, wcatT, 8192, 5120, 1024, qkvg, 4096, 4096, apre, 1024);
  scan_pass1<<<dim3(128, 4), dim3(256), 0, stream>>>(qkvg, apre, Asum, Ysum);
  scan_pass2<<<dim3(8), dim3(256), 0, stream>>>(Asum, Ysum, carry);
  scan_pass3<<<dim3(128, 4), dim3(256), 0, stream>>>(qkvg, apre, carry, yact);
  gemm128<<<dim3(8, 64), dim3(256), 0, stream>>>(
      yact, woT, 8192, 1024, 1024, (__hip_bfloat16*)nullptr, 0, 0, out, 1024);
}

// Round 14
// 186.252 us; speedup vs baseline: 1.0369x; 1.0105x over previous
//
#include <hip/hip_runtime.h>
#include <hip/hip_bf16.h>
#include <hip/hip_fp16.h>
#include <cstdint>
#include <cstddef>

// ---------------------------------------------------------------------------
// GateLoop fused pipeline — round-11 optimum + fp16 apre (halved a-traffic).
// GEMM1: 8-phase 256x256 BK=64 (round-6 schedule; epilogue writes a as fp16).
// GEMM2: 128x128 ring-3 (round-6 verbatim).
// Scan: 3-pass, packed interleaved loads, L=64 chunks (512 blocks, 2/CU).
// qkvg layout: cols [0,2048) k/v interleaved, [2048,4096) q/g interleaved,
// a -> fp16 aph. B=2, S=4096, D=1024 hard-coded.
// ---------------------------------------------------------------------------

typedef __bf16 bf16x8 __attribute__((ext_vector_type(8)));
typedef float f32x4 __attribute__((ext_vector_type(4)));

__device__ __forceinline__ void gload_lds16(const void* g, void* l) {
  __builtin_amdgcn_global_load_lds(
      (const __attribute__((address_space(1))) void*)g,
      (__attribute__((address_space(3))) void*)l,
      16, 0, 0);
}

__device__ __forceinline__ bf16x8 ldfrag(const unsigned short* p) {
  return *(const bf16x8*)p;
}

__device__ __forceinline__ float bfhi(unsigned int u) {
  union { unsigned int i; float f; } c; c.i = u & 0xffff0000u; return c.f;
}
__device__ __forceinline__ float bflo(unsigned int u) {
  union { unsigned int i; float f; } c; c.i = u << 16; return c.f;
}

#define MFMA16(acc_, a_, b_) \
  acc_ = __builtin_amdgcn_mfma_f32_16x16x32_bf16(a_, b_, acc_, 0, 0, 0)

// ---------------------------------------------------------------------------
// Weight convert + transpose with interleave row mapping:
//   k -> row 2n, v -> row 2n+1, q -> row 2048+2n, g -> row 2048+2n+1,
//   a -> row 4096+n, wo -> woT row n.
// ---------------------------------------------------------------------------
__global__ __launch_bounds__(256) void wconv_k(
    const float* __restrict__ wq, const float* __restrict__ wk,
    const float* __restrict__ wv, const float* __restrict__ wa,
    const float* __restrict__ wg, const float* __restrict__ wo,
    __hip_bfloat16* __restrict__ wcatT, __hip_bfloat16* __restrict__ woT) {
  __shared__ float t[32][33];
  const float* src;
  __hip_bfloat16* dst;
  int rmul, roff;
  switch (blockIdx.z) {
    case 0: src = wq; dst = wcatT; rmul = 2; roff = 2048; break;
    case 1: src = wk; dst = wcatT; rmul = 2; roff = 0;    break;
    case 2: src = wv; dst = wcatT; rmul = 2; roff = 1;    break;
    case 3: src = wg; dst = wcatT; rmul = 2; roff = 2049; break;
    case 4: src = wa; dst = wcatT; rmul = 1; roff = 4096; break;
    default: src = wo; dst = woT;  rmul = 1; roff = 0;    break;
  }
  const int n0 = blockIdx.x * 32;
  const int k0 = blockIdx.y * 32;
  const int tx = threadIdx.x, ty = threadIdx.y;  // (32, 8)
#pragma unroll
  for (int i = 0; i < 32; i += 8)
    t[ty + i][tx] = src[(size_t)(k0 + ty + i) * 1024 + n0 + tx];
  __syncthreads();
#pragma unroll
  for (int i = 0; i < 32; i += 8)
    dst[(size_t)(roff + rmul * (n0 + ty + i)) * 1024 + k0 + tx] =
        __float2bfloat16(t[tx][ty + i]);
}

// ---------------------------------------------------------------------------
// RMSNorm (sum-of-squares variant): xn = x * gamma * sqrt(D) * rsqrt(ss+eps)
// ---------------------------------------------------------------------------
__global__ __launch_bounds__(256) void rmsnorm_k(
    const float* __restrict__ x, const float* __restrict__ gamma,
    __hip_bfloat16* __restrict__ xn) {
  const int row = blockIdx.x;
  const int tid = threadIdx.x;
  const float4 xv = ((const float4*)(x + (size_t)row * 1024))[tid];
  float ss = xv.x * xv.x + xv.y * xv.y + xv.z * xv.z + xv.w * xv.w;
#pragma unroll
  for (int off = 32; off >= 1; off >>= 1) ss += __shfl_xor(ss, off, 64);
  __shared__ float wss[4];
  if ((tid & 63) == 0) wss[tid >> 6] = ss;
  __syncthreads();
  const float total = wss[0] + wss[1] + wss[2] + wss[3];
  const float scale = rsqrtf(total + 1e-5f) * 32.0f;  // sqrt(1024) = 32
  const float4 gv = ((const float4*)gamma)[tid];
  union { __hip_bfloat16 h[4]; ushort4 u; } ob;
  ob.h[0] = __float2bfloat16(xv.x * gv.x * scale);
  ob.h[1] = __float2bfloat16(xv.y * gv.y * scale);
  ob.h[2] = __float2bfloat16(xv.z * gv.z * scale);
  ob.h[3] = __float2bfloat16(xv.w * gv.w * scale);
  ((ushort4*)(xn + (size_t)row * 1024))[tid] = ob.u;
}

// ---------------------------------------------------------------------------
// gemm256p: 8-phase pipeline (round-6 schedule). Output: col < nbcols ->
// bf16 outb; else fp16 outh at col-nbcols (pre-sigmoid a, fp16 keeps the
// decay information that post-sigmoid rounding would destroy).
// ---------------------------------------------------------------------------
__global__ __launch_bounds__(512, 2) void gemm256p(
    const __hip_bfloat16* __restrict__ A, const __hip_bfloat16* __restrict__ Bt,
    int M, int N, int K,
    __hip_bfloat16* __restrict__ outb, int ldb, int nbcols,
    __half* __restrict__ outh, int ldh) {
  __shared__ __align__(16) unsigned short lds[65536];  // 128 KiB
  unsigned short* Asl = lds;           // [2][2][128][64] : dbuf*16384 + ht*8192
  unsigned short* Bsl = lds + 32768;

  const int tid = threadIdx.x;
  const int nwg = gridDim.x * gridDim.y;
  const int bid = blockIdx.y * gridDim.x + blockIdx.x;
  const int swz = (bid & 7) * (nwg >> 3) + (bid >> 3);
  const int brow = (swz / gridDim.x) * 256;
  const int bcol = (swz % gridDim.x) * 256;

  const unsigned short* Ag = (const unsigned short*)A + (size_t)brow * K;
  const unsigned short* Bg = (const unsigned short*)Bt + (size_t)bcol * K;

  const int sr = tid >> 3;  // 0..63
  const int sc = tid & 7;   // 16B chunk 0..7

  auto stage = [&](unsigned short* dst, const unsigned short* G, int ht, int T) {
#pragma unroll
    for (int j = 0; j < 2; ++j) {
      const int row = sr + j * 64;
      gload_lds16(G + (size_t)(ht * 128 + row) * K + T * 64 + ((sc ^ (row & 7)) << 3),
                  dst + row * 64 + sc * 8);
    }
  };

  const int lane = tid & 63;
  const int wid = tid >> 6;
  const int wr = wid >> 2;
  const int wc = wid & 3;
  const int l16 = lane & 15;
  const int k8 = lane >> 4;

  int aoff[8], boff[4];
#pragma unroll
  for (int m = 0; m < 8; ++m) {
    const int row = wr * 128 + m * 16 + l16;
    const int ht = row >> 7, hr = row & 127;
    aoff[m] = ht * 8192 + hr * 64 + ((k8 ^ (hr & 7)) << 3);
  }
#pragma unroll
  for (int n = 0; n < 4; ++n) {
    const int row = wc * 64 + n * 16 + l16;
    const int ht = row >> 7, hr = row & 127;
    boff[n] = ht * 8192 + hr * 64 + ((k8 ^ (hr & 7)) << 3);
  }

  f32x4 acc[8][4];
#pragma unroll
  for (int m = 0; m < 8; ++m)
#pragma unroll
    for (int n = 0; n < 4; ++n) acc[m][n] = (f32x4){0.f, 0.f, 0.f, 0.f};

  const int NT = K >> 6;

  stage(Asl, Ag, 0, 0);          stage(Asl + 8192, Ag, 1, 0);
  stage(Bsl, Bg, 0, 0);          stage(Bsl + 8192, Bg, 1, 0);
  stage(Bsl + 16384, Bg, 0, 1);  stage(Bsl + 16384 + 8192, Bg, 1, 1);
  asm volatile("s_waitcnt vmcnt(4)" ::: "memory");
  __builtin_amdgcn_s_barrier();

  bf16x8 aL[4][2], aH[4][2], bL[2][2], bH[2][2];

  for (int i = 0; i < NT / 2; ++i) {
    const int T1 = 2 * i + 1, T2 = 2 * i + 2, T3 = 2 * i + 3;
    const unsigned short* A0 = Asl;
    const unsigned short* B0 = Bsl;
    const unsigned short* A1 = Asl + 16384;
    const unsigned short* B1 = Bsl + 16384;

    // P1
#pragma unroll
    for (int m = 0; m < 4; ++m) {
      aL[m][0] = ldfrag(A0 + aoff[m]);
      aL[m][1] = ldfrag(A0 + (aoff[m] ^ 32));
    }
#pragma unroll
    for (int n = 0; n < 2; ++n) {
      bL[n][0] = ldfrag(B0 + boff[n]);
      bL[n][1] = ldfrag(B0 + (boff[n] ^ 32));
    }
    stage(Asl + 16384, Ag, 0, T1);
    asm volatile("s_waitcnt lgkmcnt(8)" ::: "memory");
    __builtin_amdgcn_s_barrier();
    asm volatile("s_waitcnt lgkmcnt(0)" ::: "memory");
    __builtin_amdgcn_s_setprio(1);
#pragma unroll
    for (int m = 0; m < 4; ++m)
#pragma unroll
      for (int n = 0; n < 2; ++n) {
        MFMA16(acc[m][n], aL[m][0], bL[n][0]);
        MFMA16(acc[m][n], aL[m][1], bL[n][1]);
      }
    __builtin_amdgcn_s_setprio(0);
    __builtin_amdgcn_s_barrier();

    // P2
#pragma unroll
    for (int n = 0; n < 2; ++n) {
      bH[n][0] = ldfrag(B0 + boff[2 + n]);
      bH[n][1] = ldfrag(B0 + (boff[2 + n] ^ 32));
    }
    stage(Asl + 16384 + 8192, Ag, 1, T1);
    __builtin_amdgcn_s_barrier();
    asm volatile("s_waitcnt lgkmcnt(0)" ::: "memory");
    __builtin_amdgcn_s_setprio(1);
#pragma unroll
    for (int m = 0; m < 4; ++m)
#pragma unroll
      for (int n = 0; n < 2; ++n) {
        MFMA16(acc[m][2 + n], aL[m][0], bH[n][0]);
        MFMA16(acc[m][2 + n], aL[m][1], bH[n][1]);
      }
    __builtin_amdgcn_s_setprio(0);
    __builtin_amdgcn_s_barrier();

    // P3
#pragma unroll
    for (int m = 0; m < 4; ++m) {
      aH[m][0] = ldfrag(A0 + aoff[4 + m]);
      aH[m][1] = ldfrag(A0 + (aoff[4 + m] ^ 32));
    }
    if (T2 < NT) stage(Bsl, Bg, 0, T2);
    __builtin_amdgcn_s_barrier();
    asm volatile("s_waitcnt lgkmcnt(0)" ::: "memory");
    __builtin_amdgcn_s_setprio(1);
#pragma unroll
    for (int m = 0; m < 4; ++m)
#pragma unroll
      for (int n = 0; n < 2; ++n) {
        MFMA16(acc[4 + m][2 + n], aH[m][0], bH[n][0]);
        MFMA16(acc[4 + m][2 + n], aH[m][1], bH[n][1]);
      }
    __builtin_amdgcn_s_setprio(0);
    __builtin_amdgcn_s_barrier();

    // P4
    if (T2 < NT) {
      stage(Bsl + 8192, Bg, 1, T2);
      asm volatile("s_waitcnt vmcnt(4)" ::: "memory");
    } else {
      asm volatile("s_waitcnt vmcnt(0)" ::: "memory");
    }
    __builtin_amdgcn_s_barrier();
    __builtin_amdgcn_s_setprio(1);
#pragma unroll
    for (int m = 0; m < 4; ++m)
#pragma unroll
      for (int n = 0; n < 2; ++n) {
        MFMA16(acc[4 + m][n], aH[m][0], bL[n][0]);
        MFMA16(acc[4 + m][n], aH[m][1], bL[n][1]);
      }
    __builtin_amdgcn_s_setprio(0);
    __builtin_amdgcn_s_barrier();

    // P5
#pragma unroll
    for (int m = 0; m < 4; ++m) {
      aL[m][0] = ldfrag(A1 + aoff[m]);
      aL[m][1] = ldfrag(A1 + (aoff[m] ^ 32));
    }
#pragma unroll
    for (int n = 0; n < 2; ++n) {
      bL[n][0] = ldfrag(B1 + boff[n]);
      bL[n][1] = ldfrag(B1 + (boff[n] ^ 32));
    }
    if (T2 < NT) stage(Asl, Ag, 0, T2);
    asm volatile("s_waitcnt lgkmcnt(8)" ::: "memory");
    __builtin_amdgcn_s_barrier();
    asm volatile("s_waitcnt lgkmcnt(0)" ::: "memory");
    __builtin_amdgcn_s_setprio(1);
#pragma unroll
    for (int m = 0; m < 4; ++m)
#pragma unroll
      for (int n = 0; n < 2; ++n) {
        MFMA16(acc[m][n], aL[m][0], bL[n][0]);
        MFMA16(acc[m][n], aL[m][1], bL[n][1]);
      }
    __builtin_amdgcn_s_setprio(0);
    __builtin_amdgcn_s_barrier();

    // P6
#pragma unroll
    for (int n = 0; n < 2; ++n) {
      bH[n][0] = ldfrag(B1 + boff[2 + n]);
      bH[n][1] = ldfrag(B1 + (boff[2 + n] ^ 32));
    }
    if (T2 < NT) stage(Asl + 8192, Ag, 1, T2);
    __builtin_amdgcn_s_barrier();
    asm volatile("s_waitcnt lgkmcnt(0)" ::: "memory");
    __builtin_amdgcn_s_setprio(1);
#pragma unroll
    for (int m = 0; m < 4; ++m)
#pragma unroll
      for (int n = 0; n < 2; ++n) {
        MFMA16(acc[m][2 + n], aL[m][0], bH[n][0]);
        MFMA16(acc[m][2 + n], aL[m][1], bH[n][1]);
      }
    __builtin_amdgcn_s_setprio(0);
    __builtin_amdgcn_s_barrier();

    // P7
#pragma unroll
    for (int m = 0; m < 4; ++m) {
      aH[m][0] = ldfrag(A1 + aoff[4 + m]);
      aH[m][1] = ldfrag(A1 + (aoff[4 + m] ^ 32));
    }
    if (T3 < NT) stage(Bsl + 16384, Bg, 0, T3);
    __builtin_amdgcn_s_barrier();
    asm volatile("s_waitcnt lgkmcnt(0)" ::: "memory");
    __builtin_amdgcn_s_setprio(1);
#pragma unroll
    for (int m = 0; m < 4; ++m)
#pragma unroll
      for (int n = 0; n < 2; ++n) {
        MFMA16(acc[4 + m][2 + n], aH[m][0], bH[n][0]);
        MFMA16(acc[4 + m][2 + n], aH[m][1], bH[n][1]);
      }
    __builtin_amdgcn_s_setprio(0);
    __builtin_amdgcn_s_barrier();

    // P8
    if (T3 < NT) {
      stage(Bsl + 16384 + 8192, Bg, 1, T3);
      asm volatile("s_waitcnt vmcnt(4)" ::: "memory");
    } else {
      asm volatile("s_waitcnt vmcnt(0)" ::: "memory");
    }
    __builtin_amdgcn_s_barrier();
    __builtin_amdgcn_s_setprio(1);
#pragma unroll
    for (int m = 0; m < 4; ++m)
#pragma unroll
      for (int n = 0; n < 2; ++n) {
        MFMA16(acc[4 + m][n], aH[m][0], bL[n][0]);
        MFMA16(acc[4 + m][n], aH[m][1], bL[n][1]);
      }
    __builtin_amdgcn_s_setprio(0);
    __builtin_amdgcn_s_barrier();
  }

  const int mb = brow + wr * 128 + k8 * 4;
  const int nb = bcol + wc * 64 + l16;
#pragma unroll
  for (int m = 0; m < 8; ++m) {
#pragma unroll
    for (int n = 0; n < 4; ++n) {
      const int col = nb + n * 16;
#pragma unroll
      for (int r = 0; r < 4; ++r) {
        const int row = mb + m * 16 + r;
        const float v = acc[m][n][r];
        if (col < nbcols) {
          outb[(size_t)row * ldb + col] = __float2bfloat16(v);
        } else {
          outh[(size_t)row * ldh + (col - nbcols)] = __float2half(v);
        }
      }
    }
  }
}

// ---------------------------------------------------------------------------
// gemm128: 128x128 tile, ring-3, counted vmcnt (round-6, unchanged). GEMM2.
// ---------------------------------------------------------------------------
__global__ __launch_bounds__(256) void gemm128(
    const __hip_bfloat16* __restrict__ A, const __hip_bfloat16* __restrict__ Bt,
    int M, int N, int K,
    __hip_bfloat16* __restrict__ outb, int ldb, int nbcols,
    float* __restrict__ outf, int ldf) {
  __shared__ __align__(16) unsigned short As[3 * 4096];
  __shared__ __align__(16) unsigned short Bs[3 * 4096];

  const int tid = threadIdx.x;
  const int nwg = gridDim.x * gridDim.y;
  const int bid = blockIdx.y * gridDim.x + blockIdx.x;
  const int swz = (bid & 7) * (nwg >> 3) + (bid >> 3);
  const int brow = (swz / gridDim.x) * 128;
  const int bcol = (swz % gridDim.x) * 128;

  const unsigned short* Ag = (const unsigned short*)A + (size_t)brow * K;
  const unsigned short* Bg = (const unsigned short*)Bt + (size_t)bcol * K;

  const int srow = tid >> 2;
  const int gch8 = (((tid & 3) ^ ((tid >> 3) & 3)) << 3);

  auto stageAB = [&](int sl, int slot) {
    unsigned short* dA = As + slot * 4096;
    unsigned short* dB = Bs + slot * 4096;
    const int k0 = sl << 5;
    gload_lds16(Ag + (size_t)srow * K + k0 + gch8, dA + tid * 8);
    gload_lds16(Ag + (size_t)(srow + 64) * K + k0 + gch8, dA + 2048 + tid * 8);
    gload_lds16(Bg + (size_t)srow * K + k0 + gch8, dB + tid * 8);
    gload_lds16(Bg + (size_t)(srow + 64) * K + k0 + gch8, dB + 2048 + tid * 8);
  };

  const int lane = tid & 63;
  const int wid = tid >> 6;
  const int wr = wid >> 1;
  const int wc = wid & 1;
  const int l16 = lane & 15;
  const int k8 = lane >> 4;

  int aoff[4], boff[4];
#pragma unroll
  for (int m = 0; m < 4; ++m) {
    const int r = wr * 64 + m * 16 + l16;
    aoff[m] = r * 32 + ((k8 ^ ((r >> 1) & 3)) << 3);
  }
#pragma unroll
  for (int n = 0; n < 4; ++n) {
    const int r = wc * 64 + n * 16 + l16;
    boff[n] = r * 32 + ((k8 ^ ((r >> 1) & 3)) << 3);
  }

  f32x4 acc[4][4];
#pragma unroll
  for (int m = 0; m < 4; ++m)
#pragma unroll
    for (int n = 0; n < 4; ++n) acc[m][n] = (f32x4){0.f, 0.f, 0.f, 0.f};

  const int NS = K >> 5;
  stageAB(0, 0);
  stageAB(1, 1);
  asm volatile("s_waitcnt vmcnt(4)" ::: "memory");
  __builtin_amdgcn_s_barrier();

  int rs = 0, ws = 2;
  for (int s = 0; s < NS; ++s) {
    if (s + 2 < NS) stageAB(s + 2, ws);
    const unsigned short* As_s = As + rs * 4096;
    const unsigned short* Bs_s = Bs + rs * 4096;
    bf16x8 af[4], bfr[4];
#pragma unroll
    for (int m = 0; m < 4; ++m) af[m] = *(const bf16x8*)(As_s + aoff[m]);
#pragma unroll
    for (int n = 0; n < 4; ++n) bfr[n] = *(const bf16x8*)(Bs_s + boff[n]);
    __builtin_amdgcn_s_setprio(1);
#pragma unroll
    for (int m = 0; m < 4; ++m)
#pragma unroll
      for (int n = 0; n < 4; ++n)
        acc[m][n] = __builtin_amdgcn_mfma_f32_16x16x32_bf16(af[m], bfr[n], acc[m][n], 0, 0, 0);
    __builtin_amdgcn_s_setprio(0);
    if (s <= NS - 3) {
      asm volatile("s_waitcnt vmcnt(4)" ::: "memory");
      __builtin_amdgcn_s_barrier();
    } else if (s == NS - 2) {
      asm volatile("s_waitcnt vmcnt(0)" ::: "memory");
      __builtin_amdgcn_s_barrier();
    }
    rs = (rs == 2) ? 0 : rs + 1;
    ws = (ws == 2) ? 0 : ws + 1;
  }

  const int mb = brow + wr * 64 + k8 * 4;
  const int nb = bcol + wc * 64 + l16;
#pragma unroll
  for (int m = 0; m < 4; ++m) {
#pragma unroll
    for (int n = 0; n < 4; ++n) {
      const int col = nb + n * 16;
#pragma unroll
      for (int r = 0; r < 4; ++r) {
        const int row = mb + m * 16 + r;
        const float v = acc[m][n][r];
        if (col < nbcols) {
          outb[(size_t)row * ldb + col] = __float2bfloat16(v);
        } else {
          outf[(size_t)row * ldf + (col - nbcols)] = v;
        }
      }
    }
  }
}

// ---------------------------------------------------------------------------
// Scan pass 1: per-chunk local scan, L=64. grid (128,4) x 256 thr (2 blk/CU).
// blockIdx.x = b*64 + chunk. kv packed 4B (low=k, high=v); a from fp16 aph.
// ---------------------------------------------------------------------------
__global__ __launch_bounds__(256) void scan_pass1(
    const __hip_bfloat16* __restrict__ qkvg, const __half* __restrict__ aph,
    float* __restrict__ Asum, float* __restrict__ Ysum) {
  const int bc = blockIdx.x;           // b*64 + chunk
  const int d = blockIdx.y * 256 + threadIdx.x;
  const size_t rowbase = (size_t)(bc >> 6) * 4096 + (size_t)(bc & 63) * 64;
  const unsigned int* kvp = (const unsigned int*)qkvg;  // row = 2048 uints
  float y = 0.f, Ap = 1.f;
  for (int s = 0; s < 64; ++s) {
    const size_t r = rowbase + s;
    const unsigned int kv = kvp[r * 2048 + d];
    const float ap = __half2float(aph[r * 1024 + d]);
    const float a = 1.f / (1.f + __expf(-ap));
    y = fmaf(a, y, bflo(kv) * bfhi(kv));
    Ap *= a;
  }
  Asum[(size_t)bc * 1024 + d] = Ap;
  Ysum[(size_t)bc * 1024 + d] = y;
}

// ---------------------------------------------------------------------------
// Scan pass 2: carry recurrence across 64 chunks per sequence.
// ---------------------------------------------------------------------------
__global__ __launch_bounds__(256) void scan_pass2(
    const float* __restrict__ Asum, const float* __restrict__ Ysum,
    float* __restrict__ carry) {
  const int idx = blockIdx.x * 256 + threadIdx.x;  // 0..2047
  const int b = idx >> 10, d = idx & 1023;
  float y = 0.f;
  for (int c = 0; c < 64; ++c) {
    const size_t o = (size_t)(b * 64 + c) * 1024 + d;
    carry[o] = y;
    y = fmaf(Asum[o], y, Ysum[o]);
  }
}

// ---------------------------------------------------------------------------
// Scan pass 3: rescan with carry-in, write yact. grid (128,4) x 256 thr.
// qg packed 4B (low=q, high=g); a from fp16 aph.
// ---------------------------------------------------------------------------
__global__ __launch_bounds__(256) void scan_pass3(
    const __hip_bfloat16* __restrict__ qkvg, const __half* __restrict__ aph,
    const float* __restrict__ carry, __hip_bfloat16* __restrict__ yact) {
  const int bc = blockIdx.x;
  const int d = blockIdx.y * 256 + threadIdx.x;
  const size_t rowbase = (size_t)(bc >> 6) * 4096 + (size_t)(bc & 63) * 64;
  float y = carry[(size_t)bc * 1024 + d];
  const unsigned int* kvp = (const unsigned int*)qkvg;
  for (int s = 0; s < 64; ++s) {
    const size_t r = rowbase + s;
    const unsigned int kv = kvp[r * 2048 + d];
    const unsigned int qg = kvp[r * 2048 + 1024 + d];
    const float ap = __half2float(aph[r * 1024 + d]);
    const float a = 1.f / (1.f + __expf(-ap));
    y = fmaf(a, y, bflo(kv) * bfhi(kv));
    const float gg = bfhi(qg);
    const float sg = 1.f / (1.f + __expf(-gg));
    yact[r * 1024 + d] = __float2bfloat16(bflo(qg) * y * gg * sg);
  }
}

// ---------------------------------------------------------------------------
// launch
// ---------------------------------------------------------------------------
extern "C" void kernel_launch(void* const* d_in, const int* in_sizes, int n_in,
                              void* d_out, int out_size, void* d_ws, size_t ws_size,
                              hipStream_t stream) {
  const float* x     = (const float*)d_in[0];
  const float* gamma = (const float*)d_in[1];
  const float* wq    = (const float*)d_in[2];
  const float* wk    = (const float*)d_in[3];
  const float* wv    = (const float*)d_in[4];
  const float* wa    = (const float*)d_in[5];
  const float* wg    = (const float*)d_in[6];
  const float* wo    = (const float*)d_in[7];
  float* out = (float*)d_out;

  char* ws = (char*)d_ws;
  __hip_bfloat16* wcatT = (__hip_bfloat16*)(ws);              // 5120x1024 bf16
  __hip_bfloat16* woT   = (__hip_bfloat16*)(ws + 10485760);   // 1024x1024 bf16
  __hip_bfloat16* xn    = (__hip_bfloat16*)(ws + 12582912);   // 8192x1024 bf16
  __hip_bfloat16* qkvg  = (__hip_bfloat16*)(ws + 29360128);   // 8192x4096 bf16
  __half*         aph   = (__half*)(ws + 96468992);           // 8192x1024 fp16
  __hip_bfloat16* yact  = (__hip_bfloat16*)(ws + 130023424);  // 8192x1024 bf16
  // Asum/Ysum/carry (128x1024 f32 = 512 KB each) reuse xn's region — xn is
  // dead after gemm256p completes (stream-ordered before scan_pass1).
  float*          Asum  = (float*)(ws + 12582912);
  float*          Ysum  = (float*)(ws + 12582912 + 524288);
  float*          carry = (float*)(ws + 12582912 + 1048576);

  wconv_k<<<dim3(32, 32, 6), dim3(32, 8, 1), 0, stream>>>(wq, wk, wv, wa, wg, wo, wcatT, woT);
  rmsnorm_k<<<dim3(8192), dim3(256), 0, stream>>>(x, gamma, xn);
  gemm256p<<<dim3(20, 32), dim3(512), 0, stream>>>(
      xn, wcatT, 8192, 5120, 1024, qkvg, 4096, 4096, aph, 1024);
  scan_pass1<<<dim3(128, 4), dim3(256), 0, stream>>>(qkvg, aph, Asum, Ysum);
  scan_pass2<<<dim3(8), dim3(256), 0, stream>>>(Asum, Ysum, carry);
  scan_pass3<<<dim3(128, 4), dim3(256), 0, stream>>>(qkvg, aph, carry, yact);
  gemm128<<<dim3(8, 64), dim3(256), 0, stream>>>(
      yact, woT, 8192, 1024, 1024, (__hip_bfloat16*)nullptr, 0, 0, out, 1024);
}